// Round 2
// baseline (227.172 us; speedup 1.0000x reference)
//
#include <hip/hip_runtime.h>

typedef unsigned short u16;
typedef __attribute__((ext_vector_type(8))) short bf16x8;
typedef __attribute__((ext_vector_type(4))) float f32x4;

__device__ __forceinline__ float bf2f(u16 u) {
  union { unsigned u; float f; } c; c.u = ((unsigned)u) << 16; return c.f;
}
__device__ __forceinline__ u16 f2bf(float f) {
  union { float f; unsigned u; } c; c.f = f;
  unsigned u = c.u;
  return (u16)((u + 0x7FFFu + ((u >> 16) & 1u)) >> 16);
}
// async global->LDS, 16B per lane; LDS dest = wave-uniform base + lane*16
__device__ __forceinline__ void gld16(const void* g, void* l) {
  __builtin_amdgcn_global_load_lds(
      (__attribute__((address_space(1))) void*)g,
      (__attribute__((address_space(3))) void*)l, 16, 0, 0);
}

#define BB 32      // batch
#define CC 256     // channels
#define NN 1024    // H*W

// ---------------- 0. convert weights/biases fp32 -> bf16 --------------------
__global__ __launch_bounds__(256) void convert_w_kernel(
    const float* __restrict__ Wk, const float* __restrict__ bk,
    const float* __restrict__ Wp, const float* __restrict__ bp,
    u16* __restrict__ Wkb, u16* __restrict__ bkb,
    u16* __restrict__ Wpb, u16* __restrict__ bpb)
{
  int b = blockIdx.x, t = threadIdx.x;
  const float* src; u16* dst; int idx, n;
  if (b < 768)       { src = Wk; dst = Wkb; idx = b * 256 + t;        n = 196608; }
  else if (b < 771)  { src = bk; dst = bkb; idx = (b - 768) * 256 + t; n = 768;   }
  else if (b < 1027) { src = Wp; dst = Wpb; idx = (b - 771) * 256 + t; n = 65536; }
  else               { src = bp; dst = bpb; idx = t;                  n = 256;    }
  if (idx < n) dst[idx] = f2bf(src[idx]);
}

// ---------------- 1. BatchNorm stats: per-channel mean/var -> scale/shift ----
__global__ __launch_bounds__(256) void bn_stats_kernel(
    const float* __restrict__ x, const float* __restrict__ gamma,
    const float* __restrict__ beta, float* __restrict__ scl, float* __restrict__ sft)
{
  int c = blockIdx.x;
  int tid = threadIdx.x;
  float s = 0.f, q = 0.f;
  for (int g = tid; g < 8192; g += 256) {
    int b = g >> 8;
    int n = (g & 255) * 4;
    float4 v = *reinterpret_cast<const float4*>(x + (((size_t)(b * CC + c)) << 10) + n);
    s += v.x + v.y + v.z + v.w;
    q += v.x * v.x + v.y * v.y + v.z * v.z + v.w * v.w;
  }
  __shared__ float rs[256], rq[256];
  rs[tid] = s; rq[tid] = q;
  __syncthreads();
  for (int off = 128; off > 0; off >>= 1) {
    if (tid < off) { rs[tid] += rs[tid + off]; rq[tid] += rq[tid + off]; }
    __syncthreads();
  }
  if (tid == 0) {
    float mean = rs[0] * (1.f / 32768.f);
    float var  = rq[0] * (1.f / 32768.f) - mean * mean;
    float rstd = rsqrtf(var + 1e-5f);
    float g = gamma[c] * rstd;
    scl[c] = g;
    sft[c] = beta[c] - mean * g;
  }
}

// ---------------- 2. normalize + transpose [B,C,N] -> t[B,N,C] (bf16) -------
__global__ __launch_bounds__(256) void norm_transpose_kernel(
    const float* __restrict__ x, const float* __restrict__ scl,
    const float* __restrict__ sft, u16* __restrict__ t)
{
  __shared__ float tile[64][65];
  int b = blockIdx.z, n0 = blockIdx.x * 64, c0 = blockIdx.y * 64;
  int tid = threadIdx.x;
  int hi = tid >> 4, lo4 = (tid & 15) * 4;
  #pragma unroll
  for (int r = 0; r < 4; ++r) {
    int cl = r * 16 + hi;
    int c = c0 + cl;
    float4 v = *reinterpret_cast<const float4*>(
        x + (((size_t)(b * CC + c)) << 10) + n0 + lo4);
    float sc = scl[c], sh = sft[c];
    tile[cl][lo4 + 0] = v.x * sc + sh;
    tile[cl][lo4 + 1] = v.y * sc + sh;
    tile[cl][lo4 + 2] = v.z * sc + sh;
    tile[cl][lo4 + 3] = v.w * sc + sh;
  }
  __syncthreads();
  #pragma unroll
  for (int r = 0; r < 4; ++r) {
    int nl = r * 16 + hi;
    ushort4 o;
    o.x = f2bf(tile[lo4 + 0][nl]);
    o.y = f2bf(tile[lo4 + 1][nl]);
    o.z = f2bf(tile[lo4 + 2][nl]);
    o.w = f2bf(tile[lo4 + 3][nl]);
    *reinterpret_cast<ushort4*>(t + ((size_t)(b * NN + n0 + nl)) * CC + c0 + lo4) = o;
  }
}

// ---------------- 3. NT bf16 GEMM, m97 structure (global_load_lds staging) ---
// C[m,n] = f(scale * sum_k A[m,k]*B[n,k] + bias[n])
// mode 0: plain bf16 store
// mode 1: transposed store vt[rr>>10][col][rr&1023] (bf16, ushort4)
// mode 2: proj + residual: outf[(b*256+col)<<10 | n] = v + xres[...] (fp32)
__global__ __launch_bounds__(256) void gemm_nt_kernel(
    const u16* __restrict__ A, int lda, size_t sA,
    const u16* __restrict__ B, int ldb, size_t sB,
    u16* __restrict__ C, int ldc, size_t sC,
    int K, const u16* __restrict__ bias, float scale, int mode,
    const float* __restrict__ xres, float* __restrict__ outf)
{
  __shared__ u16 As[128 * 32];   // unpadded: global_load_lds needs lane-contiguous
  __shared__ u16 Bs[128 * 32];
  int tid = threadIdx.x;
  int m0 = blockIdx.x * 128, n0 = blockIdx.y * 128;
  const u16* Ab = A + (size_t)blockIdx.z * sA;
  const u16* Bb = B + (size_t)blockIdx.z * sB;
  u16* Cb = C + (size_t)blockIdx.z * sC;

  int lane = tid & 63, w = tid >> 6;
  int lq = lane & 15, quad = lane >> 4;
  int wm = (w >> 1) * 64, wn = (w & 1) * 64;
  int ar = lane >> 2, ac = (lane & 3) * 8;   // staging: 4 lanes/row, 16B each
  int rb = w * 32;                            // wave's 32-row staging slice

  f32x4 zero = {0.f, 0.f, 0.f, 0.f};
  f32x4 acc[4][4];
  #pragma unroll
  for (int i = 0; i < 4; ++i)
    #pragma unroll
    for (int j = 0; j < 4; ++j) acc[i][j] = zero;

  for (int k0 = 0; k0 < K; k0 += 32) {
    __syncthreads();   // previous tile's ds_reads complete before overwrite
    gld16(Ab + (size_t)(m0 + rb +      ar) * lda + k0 + ac, &As[(rb     ) * 32]);
    gld16(Ab + (size_t)(m0 + rb + 16 + ar) * lda + k0 + ac, &As[(rb + 16) * 32]);
    gld16(Bb + (size_t)(n0 + rb +      ar) * ldb + k0 + ac, &Bs[(rb     ) * 32]);
    gld16(Bb + (size_t)(n0 + rb + 16 + ar) * ldb + k0 + ac, &Bs[(rb + 16) * 32]);
    __syncthreads();   // compiler drains vmcnt before barrier
    bf16x8 af[4], bfr[4];
    #pragma unroll
    for (int i = 0; i < 4; ++i) {
      af[i]  = *reinterpret_cast<const bf16x8*>(&As[(wm + i * 16 + lq) * 32 + quad * 8]);
      bfr[i] = *reinterpret_cast<const bf16x8*>(&Bs[(wn + i * 16 + lq) * 32 + quad * 8]);
    }
    #pragma unroll
    for (int i = 0; i < 4; ++i)
      #pragma unroll
      for (int j = 0; j < 4; ++j)
        acc[i][j] = __builtin_amdgcn_mfma_f32_16x16x32_bf16(af[i], bfr[j], acc[i][j], 0, 0, 0);
  }

  #pragma unroll
  for (int j = 0; j < 4; ++j) {
    int col = n0 + wn + j * 16 + lq;
    float bv = bias ? bf2f(bias[col]) : 0.f;
    #pragma unroll
    for (int i = 0; i < 4; ++i) {
      int rbase = m0 + wm + i * 16 + quad * 4;
      if (mode == 2) {
        int b = rbase >> 10, n = rbase & 1023;
        size_t idx = (((size_t)(b * CC + col)) << 10) + n;
        float4 xv = *reinterpret_cast<const float4*>(xres + idx);
        float4 o;
        o.x = acc[i][j][0] * scale + bv + xv.x;
        o.y = acc[i][j][1] * scale + bv + xv.y;
        o.z = acc[i][j][2] * scale + bv + xv.z;
        o.w = acc[i][j][3] * scale + bv + xv.w;
        *reinterpret_cast<float4*>(outf + idx) = o;
      } else if (mode == 1) {
        int b = rbase >> 10, n = rbase & 1023;
        ushort4 o;
        o.x = f2bf(acc[i][j][0] * scale + bv);
        o.y = f2bf(acc[i][j][1] * scale + bv);
        o.z = f2bf(acc[i][j][2] * scale + bv);
        o.w = f2bf(acc[i][j][3] * scale + bv);
        *reinterpret_cast<ushort4*>(&Cb[(size_t)b * 262144 + (size_t)col * 1024 + n]) = o;
      } else {
        #pragma unroll
        for (int r = 0; r < 4; ++r)
          Cb[(size_t)(rbase + r) * ldc + col] = f2bf(acc[i][j][r] * scale + bv);
      }
    }
  }
}

// ---------------- 4. fused attention: O = softmax(Q K^T / 16) V -------------
// One block = 128 Q-rows of one batch; 4 waves x 32 rows. K/V tiles of 64
// double-buffered in LDS; STAGE(t+1) issued BEFORE compute(t) so the
// compiler's vmcnt(0) drain at the end-of-iteration barrier lands after
// ~1500+ cycles of compute (T3 minimum 2-phase recipe, 1 barrier/tile).
__global__ __launch_bounds__(256, 1) void attn_kernel(
    const u16* __restrict__ qk,   // [B*1024, 512]: Q = cols 0:256, K = 256:512
    const u16* __restrict__ vt,   // [B, 256, 1024]: V^T per batch
    u16* __restrict__ o)          // [B*1024, 256]
{
  __shared__ __align__(16) u16 Ks[2][64 * 256];   // 2x32 KB [kr][c], chunk^=(kr&7)
  __shared__ __align__(16) u16 Vs[2][256 * 64];   // 2x32 KB [n][k],  chunk^=(n&7)
  __shared__ __align__(16) u16 Ps[4][32 * 64];    // 16 KB   [q][kcol], chunk^=(q&7)

  int bid = blockIdx.x;
  // XCD swizzle: all 8 q-tiles of one batch land on one XCD (K/V L2-resident)
  int b  = (bid & 7) + 8 * ((bid >> 3) & 3);
  int qt = bid >> 5;
  int tid = threadIdx.x, lane = tid & 63, w = tid >> 6;
  int lq = lane & 15, hh = lane >> 4;

  const u16* qb = qk + ((size_t)b << 10) * 512;
  const u16* kb = qb + 256;
  const u16* vb = vt + ((size_t)b << 18);
  int q0 = qt * 128 + w * 32;
  int wslot = tid & 192;   // wave-uniform slot base (w*64)

  // staging for one K/V tile into buffer bufi (16 gld16 per thread)
  auto stage = [&](int kt, int bufi) {
    #pragma unroll
    for (int i = 0; i < 8; ++i) {
      int slot = i * 256 + tid;
      int r = slot >> 5, c = slot & 31;
      gld16(kb + (size_t)(kt * 64 + r) * 512 + ((c ^ (r & 7)) << 3),
            &Ks[bufi][(i * 256 + wslot) * 8]);
    }
    #pragma unroll
    for (int i = 0; i < 8; ++i) {
      int slot = i * 256 + tid;
      int n = slot >> 3, c = slot & 7;
      gld16(vb + (size_t)(n << 10) + kt * 64 + ((c ^ (n & 7)) << 3),
            &Vs[bufi][(i * 256 + wslot) * 8]);
    }
  };

  // Q fragments in registers: A-frag row = lq, k = kk*32 + hh*8
  bf16x8 qf[2][8];
  #pragma unroll
  for (int qi = 0; qi < 2; ++qi)
    #pragma unroll
    for (int kk = 0; kk < 8; ++kk)
      qf[qi][kk] = *reinterpret_cast<const bf16x8*>(
          qb + (size_t)(q0 + qi * 16 + lq) * 512 + kk * 32 + hh * 8);

  f32x4 zero = {0.f, 0.f, 0.f, 0.f};
  f32x4 oacc[2][16];
  #pragma unroll
  for (int qi = 0; qi < 2; ++qi)
    #pragma unroll
    for (int nj = 0; nj < 16; ++nj) oacc[qi][nj] = zero;
  float runsum[2][4] = {{0.f, 0.f, 0.f, 0.f}, {0.f, 0.f, 0.f, 0.f}};

  u16* Pw = Ps[w];

  // prologue: stage tile 0, drain
  stage(0, 0);
  __syncthreads();

  #pragma unroll 1
  for (int kt = 0; kt < 16; ++kt) {
    int cur = kt & 1;
    // issue next tile's loads; they fly during compute below and are
    // drained by the compiler's vmcnt(0) at the end-of-iteration barrier
    if (kt < 15) stage(kt + 1, cur ^ 1);
    const u16* Kc = Ks[cur];
    const u16* Vc = Vs[cur];

    // ---- S = Q K^T for wave's 32 rows x 64 kcols ----
    f32x4 sacc[2][4];
    #pragma unroll
    for (int qi = 0; qi < 2; ++qi)
      #pragma unroll
      for (int ni = 0; ni < 4; ++ni) sacc[qi][ni] = zero;
    #pragma unroll
    for (int kk = 0; kk < 8; ++kk) {
      bf16x8 kf[4];
      #pragma unroll
      for (int ni = 0; ni < 4; ++ni) {
        int r = ni * 16 + lq;
        kf[ni] = *reinterpret_cast<const bf16x8*>(
            &Kc[r * 256 + (((kk * 4 + hh) ^ (r & 7)) << 3)]);
      }
      #pragma unroll
      for (int qi = 0; qi < 2; ++qi)
        #pragma unroll
        for (int ni = 0; ni < 4; ++ni)
          sacc[qi][ni] = __builtin_amdgcn_mfma_f32_16x16x32_bf16(
              qf[qi][kk], kf[ni], sacc[qi][ni], 0, 0, 0);
    }

    // ---- P = exp(S/16), accumulate row sums, pack bf16 into wave-private LDS
    #pragma unroll
    for (int qi = 0; qi < 2; ++qi)
      #pragma unroll
      for (int ni = 0; ni < 4; ++ni)
        #pragma unroll
        for (int rr = 0; rr < 4; ++rr) {
          float p = __expf(sacc[qi][ni][rr] * 0.0625f);
          u16 pb = f2bf(p);
          runsum[qi][rr] += bf2f(pb);    // sum rounded values (matches PV input)
          int q = qi * 16 + hh * 4 + rr;
          int kcol = ni * 16 + lq;
          Pw[q * 64 + ((((kcol >> 3) ^ (q & 7)) << 3) | (kcol & 7))] = pb;
        }

    // ---- O += P V ----
    #pragma unroll
    for (int kk2 = 0; kk2 < 2; ++kk2) {
      bf16x8 pa[2];
      #pragma unroll
      for (int qi = 0; qi < 2; ++qi) {
        int q = qi * 16 + lq;
        pa[qi] = *reinterpret_cast<const bf16x8*>(
            &Pw[q * 64 + (((kk2 * 4 + hh) ^ (q & 7)) << 3)]);
      }
      #pragma unroll
      for (int nj = 0; nj < 16; ++nj) {
        int n = nj * 16 + lq;
        bf16x8 vf = *reinterpret_cast<const bf16x8*>(
            &Vc[n * 64 + (((kk2 * 4 + hh) ^ (n & 7)) << 3)]);
        #pragma unroll
        for (int qi = 0; qi < 2; ++qi)
          oacc[qi][nj] = __builtin_amdgcn_mfma_f32_16x16x32_bf16(
              pa[qi], vf, oacc[qi][nj], 0, 0, 0);
      }
    }
    __syncthreads();   // drains next-tile loads (vmcnt 0) + P-buffer reuse
  }

  // ---- finalize: reduce row sums across the 16 kcol-lanes, scale, store ----
  #pragma unroll
  for (int qi = 0; qi < 2; ++qi)
    #pragma unroll
    for (int rr = 0; rr < 4; ++rr) {
      float s = runsum[qi][rr];
      s += __shfl_xor(s, 1, 64);
      s += __shfl_xor(s, 2, 64);
      s += __shfl_xor(s, 4, 64);
      s += __shfl_xor(s, 8, 64);
      runsum[qi][rr] = 1.f / s;
    }
  u16* ob = o + (size_t)((b << 10) + q0) * 256;
  #pragma unroll
  for (int qi = 0; qi < 2; ++qi)
    #pragma unroll
    for (int nj = 0; nj < 16; ++nj)
      #pragma unroll
      for (int rr = 0; rr < 4; ++rr)
        ob[(size_t)(qi * 16 + hh * 4 + rr) * 256 + nj * 16 + lq] =
            f2bf(oacc[qi][nj][rr] * runsum[qi][rr]);
}

extern "C" void kernel_launch(void* const* d_in, const int* in_sizes, int n_in,
                              void* d_out, int out_size, void* d_ws, size_t ws_size,
                              hipStream_t stream) {
  const float* x     = (const float*)d_in[0];
  const float* gamma = (const float*)d_in[1];
  const float* beta  = (const float*)d_in[2];
  const float* Wkqv  = (const float*)d_in[3];
  const float* bkqv  = (const float*)d_in[4];
  const float* Wproj = (const float*)d_in[5];
  const float* bproj = (const float*)d_in[6];
  float* out = (float*)d_out;          // fp32 [32,256,32,32]

  // ---- workspace layout ----
  char* ws = (char*)d_ws;
  float* scl    = (float*)ws;                   // 256 f32
  float* sft    = (float*)(ws + 1024);          // 256 f32
  u16* Wkb = (u16*)(ws + 4096);                 // 196608 bf16
  u16* bkb = Wkb + 196608;
  u16* Wpb = bkb + 768;
  u16* bpb = Wpb + 65536;
  u16* qk   = (u16*)(ws + 1048576);             // [32768,512] bf16 = 32 MB
  u16* vt   = qk + (size_t)32768 * 512;         // [32,256,1024] bf16 = 16 MB
  u16* o_pv = vt + (size_t)32 * 256 * 1024;     // [32768,256] bf16 = 16 MB
  u16* t = (u16*)d_out;   // bf16 scratch in d_out, dead before mode-2 writes

  // 0. weight conversion
  convert_w_kernel<<<dim3(1028), dim3(256), 0, stream>>>(
      Wkqv, bkqv, Wproj, bproj, Wkb, bkb, Wpb, bpb);
  // 1. BN stats
  bn_stats_kernel<<<dim3(256), dim3(256), 0, stream>>>(x, gamma, beta, scl, sft);
  // 2. normalize + transpose -> t [B,N,C]
  norm_transpose_kernel<<<dim3(16, 4, 32), dim3(256), 0, stream>>>(x, scl, sft, t);
  // 3a. qk = t @ Wkqv[0:512]^T + b[0:512]
  gemm_nt_kernel<<<dim3(256, 4, 1), dim3(256), 0, stream>>>(
      t, 256, 0, Wkb, 256, 0, qk, 512, 0, 256, bkb, 1.0f, 0, nullptr, nullptr);
  // 3b. vt[b,c,n] = (t @ Wkqv[512:768]^T + b[512:768])^T
  gemm_nt_kernel<<<dim3(256, 2, 1), dim3(256), 0, stream>>>(
      t, 256, 0, Wkb + 512 * 256, 256, 0, vt, 0, 0, 256, bkb + 512, 1.0f, 1,
      nullptr, nullptr);
  // 4. fused attention: o_pv = softmax(Q K^T / 16) V   (bf16)
  attn_kernel<<<dim3(256), dim3(256), 0, stream>>>(qk, vt, o_pv);
  // 5. fused proj + residual: out[b,c,n] = (o_pv @ Wproj^T + bproj)[n,c] + x[b,c,n]
  gemm_nt_kernel<<<dim3(256, 2, 1), dim3(256), 0, stream>>>(
      o_pv, 256, 0, Wpb, 256, 0, nullptr, 0, 0, 256, bpb, 1.0f, 2, x, out);
}

// Round 3
// 211.872 us; speedup vs baseline: 1.0722x; 1.0722x over previous
//
#include <hip/hip_runtime.h>

typedef unsigned short u16;
typedef __attribute__((ext_vector_type(8))) short bf16x8;
typedef __attribute__((ext_vector_type(4))) float f32x4;

__device__ __forceinline__ float bf2f(u16 u) {
  union { unsigned u; float f; } c; c.u = ((unsigned)u) << 16; return c.f;
}
__device__ __forceinline__ u16 f2bf(float f) {
  union { float f; unsigned u; } c; c.f = f;
  unsigned u = c.u;
  return (u16)((u + 0x7FFFu + ((u >> 16) & 1u)) >> 16);
}
// async global->LDS, 16B per lane; LDS dest = wave-uniform base + lane*16
__device__ __forceinline__ void gld16(const void* g, void* l) {
  __builtin_amdgcn_global_load_lds(
      (__attribute__((address_space(1))) void*)g,
      (__attribute__((address_space(3))) void*)l, 16, 0, 0);
}

// drain own counters, then workgroup barrier (used in wave-role-divergent
// code where __syncthreads' convergence assumption doesn't hold; barrier
// counts are matched exactly across roles). sched_barrier stops hipcc from
// hoisting ds_reads/MFMA across the asm waitcnt (guide rule #18).
#define SYNCB() do { \
  asm volatile("s_waitcnt vmcnt(0) lgkmcnt(0)" ::: "memory"); \
  __builtin_amdgcn_s_barrier(); \
  __builtin_amdgcn_sched_barrier(0); \
} while (0)

#define BB 32      // batch
#define CC 256     // channels
#define NN 1024    // H*W

// ---------------- 0. convert weights/biases fp32 -> bf16 --------------------
__global__ __launch_bounds__(256) void convert_w_kernel(
    const float* __restrict__ Wk, const float* __restrict__ bk,
    const float* __restrict__ Wp, const float* __restrict__ bp,
    u16* __restrict__ Wkb, u16* __restrict__ bkb,
    u16* __restrict__ Wpb, u16* __restrict__ bpb)
{
  int b = blockIdx.x, t = threadIdx.x;
  const float* src; u16* dst; int idx, n;
  if (b < 768)       { src = Wk; dst = Wkb; idx = b * 256 + t;        n = 196608; }
  else if (b < 771)  { src = bk; dst = bkb; idx = (b - 768) * 256 + t; n = 768;   }
  else if (b < 1027) { src = Wp; dst = Wpb; idx = (b - 771) * 256 + t; n = 65536; }
  else               { src = bp; dst = bpb; idx = t;                  n = 256;    }
  if (idx < n) dst[idx] = f2bf(src[idx]);
}

// ---------------- 1. BatchNorm stats: per-channel mean/var -> scale/shift ----
__global__ __launch_bounds__(256) void bn_stats_kernel(
    const float* __restrict__ x, const float* __restrict__ gamma,
    const float* __restrict__ beta, float* __restrict__ scl, float* __restrict__ sft)
{
  int c = blockIdx.x;
  int tid = threadIdx.x;
  float s = 0.f, q = 0.f;
  for (int g = tid; g < 8192; g += 256) {
    int b = g >> 8;
    int n = (g & 255) * 4;
    float4 v = *reinterpret_cast<const float4*>(x + (((size_t)(b * CC + c)) << 10) + n);
    s += v.x + v.y + v.z + v.w;
    q += v.x * v.x + v.y * v.y + v.z * v.z + v.w * v.w;
  }
  __shared__ float rs[256], rq[256];
  rs[tid] = s; rq[tid] = q;
  __syncthreads();
  for (int off = 128; off > 0; off >>= 1) {
    if (tid < off) { rs[tid] += rs[tid + off]; rq[tid] += rq[tid + off]; }
    __syncthreads();
  }
  if (tid == 0) {
    float mean = rs[0] * (1.f / 32768.f);
    float var  = rq[0] * (1.f / 32768.f) - mean * mean;
    float rstd = rsqrtf(var + 1e-5f);
    float g = gamma[c] * rstd;
    scl[c] = g;
    sft[c] = beta[c] - mean * g;
  }
}

// ---------------- 2. normalize + transpose [B,C,N] -> t[B,N,C] (bf16) -------
__global__ __launch_bounds__(256) void norm_transpose_kernel(
    const float* __restrict__ x, const float* __restrict__ scl,
    const float* __restrict__ sft, u16* __restrict__ t)
{
  __shared__ float tile[64][65];
  int b = blockIdx.z, n0 = blockIdx.x * 64, c0 = blockIdx.y * 64;
  int tid = threadIdx.x;
  int hi = tid >> 4, lo4 = (tid & 15) * 4;
  #pragma unroll
  for (int r = 0; r < 4; ++r) {
    int cl = r * 16 + hi;
    int c = c0 + cl;
    float4 v = *reinterpret_cast<const float4*>(
        x + (((size_t)(b * CC + c)) << 10) + n0 + lo4);
    float sc = scl[c], sh = sft[c];
    tile[cl][lo4 + 0] = v.x * sc + sh;
    tile[cl][lo4 + 1] = v.y * sc + sh;
    tile[cl][lo4 + 2] = v.z * sc + sh;
    tile[cl][lo4 + 3] = v.w * sc + sh;
  }
  __syncthreads();
  #pragma unroll
  for (int r = 0; r < 4; ++r) {
    int nl = r * 16 + hi;
    ushort4 o;
    o.x = f2bf(tile[lo4 + 0][nl]);
    o.y = f2bf(tile[lo4 + 1][nl]);
    o.z = f2bf(tile[lo4 + 2][nl]);
    o.w = f2bf(tile[lo4 + 3][nl]);
    *reinterpret_cast<ushort4*>(t + ((size_t)(b * NN + n0 + nl)) * CC + c0 + lo4) = o;
  }
}

// ---------------- 3. NT bf16 GEMM, m97 structure (global_load_lds staging) ---
// C[m,n] = f(scale * sum_k A[m,k]*B[n,k] + bias[n])
// mode 0: plain bf16 store
// mode 1: transposed store vt[rr>>10][col][rr&1023] (bf16, ushort4)
// mode 2: proj + residual: outf[(b*256+col)<<10 | n] = v + xres[...] (fp32)
__global__ __launch_bounds__(256) void gemm_nt_kernel(
    const u16* __restrict__ A, int lda, size_t sA,
    const u16* __restrict__ B, int ldb, size_t sB,
    u16* __restrict__ C, int ldc, size_t sC,
    int K, const u16* __restrict__ bias, float scale, int mode,
    const float* __restrict__ xres, float* __restrict__ outf)
{
  __shared__ u16 As[128 * 32];   // unpadded: global_load_lds needs lane-contiguous
  __shared__ u16 Bs[128 * 32];
  int tid = threadIdx.x;
  int m0 = blockIdx.x * 128, n0 = blockIdx.y * 128;
  const u16* Ab = A + (size_t)blockIdx.z * sA;
  const u16* Bb = B + (size_t)blockIdx.z * sB;
  u16* Cb = C + (size_t)blockIdx.z * sC;

  int lane = tid & 63, w = tid >> 6;
  int lq = lane & 15, quad = lane >> 4;
  int wm = (w >> 1) * 64, wn = (w & 1) * 64;
  int ar = lane >> 2, ac = (lane & 3) * 8;   // staging: 4 lanes/row, 16B each
  int rb = w * 32;                            // wave's 32-row staging slice

  f32x4 zero = {0.f, 0.f, 0.f, 0.f};
  f32x4 acc[4][4];
  #pragma unroll
  for (int i = 0; i < 4; ++i)
    #pragma unroll
    for (int j = 0; j < 4; ++j) acc[i][j] = zero;

  for (int k0 = 0; k0 < K; k0 += 32) {
    __syncthreads();   // previous tile's ds_reads complete before overwrite
    gld16(Ab + (size_t)(m0 + rb +      ar) * lda + k0 + ac, &As[(rb     ) * 32]);
    gld16(Ab + (size_t)(m0 + rb + 16 + ar) * lda + k0 + ac, &As[(rb + 16) * 32]);
    gld16(Bb + (size_t)(n0 + rb +      ar) * ldb + k0 + ac, &Bs[(rb     ) * 32]);
    gld16(Bb + (size_t)(n0 + rb + 16 + ar) * ldb + k0 + ac, &Bs[(rb + 16) * 32]);
    __syncthreads();   // compiler drains vmcnt before barrier
    bf16x8 af[4], bfr[4];
    #pragma unroll
    for (int i = 0; i < 4; ++i) {
      af[i]  = *reinterpret_cast<const bf16x8*>(&As[(wm + i * 16 + lq) * 32 + quad * 8]);
      bfr[i] = *reinterpret_cast<const bf16x8*>(&Bs[(wn + i * 16 + lq) * 32 + quad * 8]);
    }
    #pragma unroll
    for (int i = 0; i < 4; ++i)
      #pragma unroll
      for (int j = 0; j < 4; ++j)
        acc[i][j] = __builtin_amdgcn_mfma_f32_16x16x32_bf16(af[i], bfr[j], acc[i][j], 0, 0, 0);
  }

  #pragma unroll
  for (int j = 0; j < 4; ++j) {
    int col = n0 + wn + j * 16 + lq;
    float bv = bias ? bf2f(bias[col]) : 0.f;
    #pragma unroll
    for (int i = 0; i < 4; ++i) {
      int rbase = m0 + wm + i * 16 + quad * 4;
      if (mode == 2) {
        int b = rbase >> 10, n = rbase & 1023;
        size_t idx = (((size_t)(b * CC + col)) << 10) + n;
        float4 xv = *reinterpret_cast<const float4*>(xres + idx);
        float4 o;
        o.x = acc[i][j][0] * scale + bv + xv.x;
        o.y = acc[i][j][1] * scale + bv + xv.y;
        o.z = acc[i][j][2] * scale + bv + xv.z;
        o.w = acc[i][j][3] * scale + bv + xv.w;
        *reinterpret_cast<float4*>(outf + idx) = o;
      } else if (mode == 1) {
        int b = rbase >> 10, n = rbase & 1023;
        ushort4 o;
        o.x = f2bf(acc[i][j][0] * scale + bv);
        o.y = f2bf(acc[i][j][1] * scale + bv);
        o.z = f2bf(acc[i][j][2] * scale + bv);
        o.w = f2bf(acc[i][j][3] * scale + bv);
        *reinterpret_cast<ushort4*>(&Cb[(size_t)b * 262144 + (size_t)col * 1024 + n]) = o;
      } else {
        #pragma unroll
        for (int r = 0; r < 4; ++r)
          Cb[(size_t)(rbase + r) * ldc + col] = f2bf(acc[i][j][r] * scale + bv);
      }
    }
  }
}

// ---------------- 4. fused attention: O = softmax(Q K^T / 16) V -------------
// Producer/consumer wave specialization: 8 waves (2 per SIMD).
// Waves 0-3 (QK role): 32 q-rows each, Q in registers; compute S(p), exp,
//   write P(p) into shared LDS between the two phase barriers.
// Waves 4-7 (PV role): 64 output-cols each x all 128 rows; compute
//   O += P(p-1) * V(p-1) -- overlaps QK(p) on the same SIMDs.
// K/V double-buffered (staged via global_load_lds, pre-swizzled source),
// P single-buffered with a 2-barrier handoff. Per-role loops with matched
// raw-barrier counts (36 each); rowsum handoff via LDS at the end.
__global__ __launch_bounds__(512, 2) void attn_kernel(
    const u16* __restrict__ qk,   // [B*1024, 512]: Q = cols 0:256, K = 256:512
    const u16* __restrict__ vt,   // [B, 256, 1024]: V^T per batch
    u16* __restrict__ o)          // [B*1024, 256]
{
  __shared__ __align__(16) u16 Ks[2][64 * 256];   // 2x32 KB [kr][c], chunk^=(kr&7)
  __shared__ __align__(16) u16 Vs[2][256 * 64];   // 2x32 KB [n][k],  chunk^=(n&7)
  __shared__ __align__(16) u16 Ps[128 * 64];      // 16 KB   [q][k],  chunk^=(q&7)
  float* rs = (float*)Ps;          // 128 f32 inv-rowsums; alias ok: P dead then

  int bid = blockIdx.x;
  // XCD swizzle: all 8 q-tiles of one batch land on one XCD (K/V L2-resident)
  int b  = (bid & 7) + 8 * ((bid >> 3) & 3);
  int qt = bid >> 5;
  int tid = threadIdx.x, lane = tid & 63, w = tid >> 6;
  int lq = lane & 15, hh = lane >> 4;
  int wr = w & 3;                  // row-group (QK) / col-group (PV)
  bool isQK = w < 4;

  const u16* qb = qk + ((size_t)b << 10) * 512;
  const u16* kb = qb + 256;
  const u16* vb = vt + ((size_t)b << 18);

  // staging: 512 threads, 4 chunks(16B) each per tile half
  auto stageK = [&](int kt, int bufi) {
    #pragma unroll
    for (int i = 0; i < 4; ++i) {
      int slot = i * 512 + tid;
      int r = slot >> 5, c = slot & 31;
      gld16(kb + (size_t)(kt * 64 + r) * 512 + ((c ^ (r & 7)) << 3),
            &Ks[bufi][(i * 512 + (tid & 448)) * 8]);
    }
  };
  auto stageV = [&](int kt, int bufi) {
    #pragma unroll
    for (int i = 0; i < 4; ++i) {
      int slot = i * 512 + tid;
      int n = slot >> 3, c = slot & 7;
      gld16(vb + (size_t)(n << 10) + kt * 64 + ((c ^ (n & 7)) << 3),
            &Vs[bufi][(i * 512 + (tid & 448)) * 8]);
    }
  };

  f32x4 zero = {0.f, 0.f, 0.f, 0.f};

  // prologue: stage K(0) into buf0 (common, uniform)
  stageK(0, 0);
  SYNCB();                                   // barrier #1

  if (isQK) {
    // ---------------- QK / softmax producer ----------------
    int q0 = qt * 128 + wr * 32;
    bf16x8 qf[2][8];
    #pragma unroll
    for (int qi = 0; qi < 2; ++qi)
      #pragma unroll
      for (int kk = 0; kk < 8; ++kk)
        qf[qi][kk] = *reinterpret_cast<const bf16x8*>(
            qb + (size_t)(q0 + qi * 16 + lq) * 512 + kk * 32 + hh * 8);
    float runsum[2][4] = {{0.f, 0.f, 0.f, 0.f}, {0.f, 0.f, 0.f, 0.f}};

    #pragma unroll 1
    for (int p = 0; p <= 16; ++p) {
      if (p <= 15) stageV(p, p & 1);
      if (p <= 14) stageK(p + 1, (p + 1) & 1);
      u16 pbv[2][4][4];
      if (p <= 15) {
        const u16* Kc = Ks[p & 1];
        f32x4 sacc[2][4];
        #pragma unroll
        for (int qi = 0; qi < 2; ++qi)
          #pragma unroll
          for (int ni = 0; ni < 4; ++ni) sacc[qi][ni] = zero;
        #pragma unroll
        for (int kk = 0; kk < 8; ++kk) {
          bf16x8 kf[4];
          #pragma unroll
          for (int ni = 0; ni < 4; ++ni) {
            int r = ni * 16 + lq;
            kf[ni] = *reinterpret_cast<const bf16x8*>(
                &Kc[r * 256 + (((kk * 4 + hh) ^ (r & 7)) << 3)]);
          }
          __builtin_amdgcn_s_setprio(1);
          #pragma unroll
          for (int qi = 0; qi < 2; ++qi)
            #pragma unroll
            for (int ni = 0; ni < 4; ++ni)
              sacc[qi][ni] = __builtin_amdgcn_mfma_f32_16x16x32_bf16(
                  qf[qi][kk], kf[ni], sacc[qi][ni], 0, 0, 0);
          __builtin_amdgcn_s_setprio(0);
        }
        // softmax numerator into regs (write deferred past barrier #1)
        #pragma unroll
        for (int qi = 0; qi < 2; ++qi)
          #pragma unroll
          for (int ni = 0; ni < 4; ++ni)
            #pragma unroll
            for (int rr = 0; rr < 4; ++rr) {
              float pexp = __expf(sacc[qi][ni][rr] * 0.0625f);
              u16 pb = f2bf(pexp);
              runsum[qi][rr] += bf2f(pb);   // sum rounded values (= PV input)
              pbv[qi][ni][rr] = pb;
            }
      }
      SYNCB();                               // phase barrier A
      if (p <= 15) {
        #pragma unroll
        for (int qi = 0; qi < 2; ++qi)
          #pragma unroll
          for (int ni = 0; ni < 4; ++ni)
            #pragma unroll
            for (int rr = 0; rr < 4; ++rr) {
              int q = wr * 32 + qi * 16 + hh * 4 + rr;
              int kcol = ni * 16 + lq;
              Ps[q * 64 + ((((kcol >> 3) ^ (q & 7)) << 3) | (kcol & 7))] =
                  pbv[qi][ni][rr];
            }
      }
      SYNCB();                               // phase barrier B
    }

    // inv-rowsums -> LDS for the PV waves
    #pragma unroll
    for (int qi = 0; qi < 2; ++qi)
      #pragma unroll
      for (int rr = 0; rr < 4; ++rr) {
        float s = runsum[qi][rr];
        s += __shfl_xor(s, 1, 64);
        s += __shfl_xor(s, 2, 64);
        s += __shfl_xor(s, 4, 64);
        s += __shfl_xor(s, 8, 64);
        if (lq == 0) rs[wr * 32 + qi * 16 + hh * 4 + rr] = 1.f / s;
      }
    SYNCB();                                 // final barrier
  } else {
    // ---------------- PV consumer ----------------
    f32x4 oacc[8][4];
    #pragma unroll
    for (int qi = 0; qi < 8; ++qi)
      #pragma unroll
      for (int nj = 0; nj < 4; ++nj) oacc[qi][nj] = zero;

    #pragma unroll 1
    for (int p = 0; p <= 16; ++p) {
      if (p <= 15) stageV(p, p & 1);
      if (p <= 14) stageK(p + 1, (p + 1) & 1);
      if (p >= 1) {
        const u16* Vc = Vs[(p - 1) & 1];
        #pragma unroll
        for (int kk2 = 0; kk2 < 2; ++kk2) {
          bf16x8 pa[8];
          #pragma unroll
          for (int qi = 0; qi < 8; ++qi) {
            int r = qi * 16 + lq;
            pa[qi] = *reinterpret_cast<const bf16x8*>(
                &Ps[r * 64 + (((kk2 * 4 + hh) ^ (r & 7)) << 3)]);
          }
          bf16x8 vf[4];
          #pragma unroll
          for (int nj = 0; nj < 4; ++nj) {
            int n = wr * 64 + nj * 16 + lq;
            vf[nj] = *reinterpret_cast<const bf16x8*>(
                &Vc[n * 64 + (((kk2 * 4 + hh) ^ (n & 7)) << 3)]);
          }
          __builtin_amdgcn_s_setprio(1);
          #pragma unroll
          for (int qi = 0; qi < 8; ++qi)
            #pragma unroll
            for (int nj = 0; nj < 4; ++nj)
              oacc[qi][nj] = __builtin_amdgcn_mfma_f32_16x16x32_bf16(
                  pa[qi], vf[nj], oacc[qi][nj], 0, 0, 0);
          __builtin_amdgcn_s_setprio(0);
        }
      }
      SYNCB();                               // phase barrier A
      SYNCB();                               // phase barrier B
    }

    SYNCB();                                 // final barrier (rowsums ready)
    float rinv[8][4];
    #pragma unroll
    for (int qi = 0; qi < 8; ++qi)
      #pragma unroll
      for (int rr = 0; rr < 4; ++rr)
        rinv[qi][rr] = rs[qi * 16 + hh * 4 + rr];
    u16* ob = o + ((size_t)(b << 10) + qt * 128) * 256;
    #pragma unroll
    for (int qi = 0; qi < 8; ++qi)
      #pragma unroll
      for (int nj = 0; nj < 4; ++nj)
        #pragma unroll
        for (int rr = 0; rr < 4; ++rr)
          ob[(size_t)(qi * 16 + hh * 4 + rr) * 256 + wr * 64 + nj * 16 + lq] =
              f2bf(oacc[qi][nj][rr] * rinv[qi][rr]);
  }
}

extern "C" void kernel_launch(void* const* d_in, const int* in_sizes, int n_in,
                              void* d_out, int out_size, void* d_ws, size_t ws_size,
                              hipStream_t stream) {
  const float* x     = (const float*)d_in[0];
  const float* gamma = (const float*)d_in[1];
  const float* beta  = (const float*)d_in[2];
  const float* Wkqv  = (const float*)d_in[3];
  const float* bkqv  = (const float*)d_in[4];
  const float* Wproj = (const float*)d_in[5];
  const float* bproj = (const float*)d_in[6];
  float* out = (float*)d_out;          // fp32 [32,256,32,32]

  // ---- workspace layout ----
  char* ws = (char*)d_ws;
  float* scl    = (float*)ws;                   // 256 f32
  float* sft    = (float*)(ws + 1024);          // 256 f32
  u16* Wkb = (u16*)(ws + 4096);                 // 196608 bf16
  u16* bkb = Wkb + 196608;
  u16* Wpb = bkb + 768;
  u16* bpb = Wpb + 65536;
  u16* qk   = (u16*)(ws + 1048576);             // [32768,512] bf16 = 32 MB
  u16* vt   = qk + (size_t)32768 * 512;         // [32,256,1024] bf16 = 16 MB
  u16* o_pv = vt + (size_t)32 * 256 * 1024;     // [32768,256] bf16 = 16 MB
  u16* t = (u16*)d_out;   // bf16 scratch in d_out, dead before mode-2 writes

  // 0. weight conversion
  convert_w_kernel<<<dim3(1028), dim3(256), 0, stream>>>(
      Wkqv, bkqv, Wproj, bproj, Wkb, bkb, Wpb, bpb);
  // 1. BN stats
  bn_stats_kernel<<<dim3(256), dim3(256), 0, stream>>>(x, gamma, beta, scl, sft);
  // 2. normalize + transpose -> t [B,N,C]
  norm_transpose_kernel<<<dim3(16, 4, 32), dim3(256), 0, stream>>>(x, scl, sft, t);
  // 3a. qk = t @ Wkqv[0:512]^T + b[0:512]
  gemm_nt_kernel<<<dim3(256, 4, 1), dim3(256), 0, stream>>>(
      t, 256, 0, Wkb, 256, 0, qk, 512, 0, 256, bkb, 1.0f, 0, nullptr, nullptr);
  // 3b. vt[b,c,n] = (t @ Wkqv[512:768]^T + b[512:768])^T
  gemm_nt_kernel<<<dim3(256, 2, 1), dim3(256), 0, stream>>>(
      t, 256, 0, Wkb + 512 * 256, 256, 0, vt, 0, 0, 256, bkb + 512, 1.0f, 1,
      nullptr, nullptr);
  // 4. fused attention (wave-specialized): o_pv = softmax(Q K^T / 16) V (bf16)
  attn_kernel<<<dim3(256), dim3(512), 0, stream>>>(qk, vt, o_pv);
  // 5. fused proj + residual: out[b,c,n] = (o_pv @ Wproj^T + bproj)[n,c] + x[b,c,n]
  gemm_nt_kernel<<<dim3(256, 2, 1), dim3(256), 0, stream>>>(
      o_pv, 256, 0, Wpb, 256, 0, nullptr, 0, 0, 256, bpb, 1.0f, 2, x, out);
}

// Round 4
// 203.815 us; speedup vs baseline: 1.1146x; 1.0395x over previous
//
#include <hip/hip_runtime.h>

typedef unsigned short u16;
typedef __attribute__((ext_vector_type(8))) short bf16x8;
typedef __attribute__((ext_vector_type(4))) float f32x4;

__device__ __forceinline__ float bf2f(u16 u) {
  union { unsigned u; float f; } c; c.u = ((unsigned)u) << 16; return c.f;
}
__device__ __forceinline__ u16 f2bf(float f) {
  union { float f; unsigned u; } c; c.f = f;
  unsigned u = c.u;
  return (u16)((u + 0x7FFFu + ((u >> 16) & 1u)) >> 16);
}
// async global->LDS, 16B per lane; LDS dest = wave-uniform base + lane*16
__device__ __forceinline__ void gld16(const void* g, void* l) {
  __builtin_amdgcn_global_load_lds(
      (__attribute__((address_space(1))) void*)g,
      (__attribute__((address_space(3))) void*)l, 16, 0, 0);
}

// drain own counters, then workgroup barrier (used in wave-role-divergent
// code where __syncthreads' convergence assumption doesn't hold; barrier
// counts are matched exactly across roles). sched_barrier stops hipcc from
// hoisting ds_reads/MFMA across the asm waitcnt (guide rule #18).
#define SYNCB() do { \
  asm volatile("s_waitcnt vmcnt(0) lgkmcnt(0)" ::: "memory"); \
  __builtin_amdgcn_s_barrier(); \
  __builtin_amdgcn_sched_barrier(0); \
} while (0)

#define BB 32      // batch
#define CC 256     // channels
#define NN 1024    // H*W

// ---------------- 0. convert weights/biases fp32 -> bf16 --------------------
__global__ __launch_bounds__(256) void convert_w_kernel(
    const float* __restrict__ Wk, const float* __restrict__ bk,
    const float* __restrict__ Wp, const float* __restrict__ bp,
    u16* __restrict__ Wkb, u16* __restrict__ bkb,
    u16* __restrict__ Wpb, u16* __restrict__ bpb)
{
  int b = blockIdx.x, t = threadIdx.x;
  const float* src; u16* dst; int idx, n;
  if (b < 768)       { src = Wk; dst = Wkb; idx = b * 256 + t;        n = 196608; }
  else if (b < 771)  { src = bk; dst = bkb; idx = (b - 768) * 256 + t; n = 768;   }
  else if (b < 1027) { src = Wp; dst = Wpb; idx = (b - 771) * 256 + t; n = 65536; }
  else               { src = bp; dst = bpb; idx = t;                  n = 256;    }
  if (idx < n) dst[idx] = f2bf(src[idx]);
}

// ---------------- 1. BatchNorm stats: per-channel mean/var -> scale/shift ----
__global__ __launch_bounds__(256) void bn_stats_kernel(
    const float* __restrict__ x, const float* __restrict__ gamma,
    const float* __restrict__ beta, float* __restrict__ scl, float* __restrict__ sft)
{
  int c = blockIdx.x;
  int tid = threadIdx.x;
  float s = 0.f, q = 0.f;
  for (int g = tid; g < 8192; g += 256) {
    int b = g >> 8;
    int n = (g & 255) * 4;
    float4 v = *reinterpret_cast<const float4*>(x + (((size_t)(b * CC + c)) << 10) + n);
    s += v.x + v.y + v.z + v.w;
    q += v.x * v.x + v.y * v.y + v.z * v.z + v.w * v.w;
  }
  __shared__ float rs[256], rq[256];
  rs[tid] = s; rq[tid] = q;
  __syncthreads();
  for (int off = 128; off > 0; off >>= 1) {
    if (tid < off) { rs[tid] += rs[tid + off]; rq[tid] += rq[tid + off]; }
    __syncthreads();
  }
  if (tid == 0) {
    float mean = rs[0] * (1.f / 32768.f);
    float var  = rq[0] * (1.f / 32768.f) - mean * mean;
    float rstd = rsqrtf(var + 1e-5f);
    float g = gamma[c] * rstd;
    scl[c] = g;
    sft[c] = beta[c] - mean * g;
  }
}

// ---------------- 2. fused QKV GEMM with on-the-fly BN-normalize+transpose --
// C[m, col] = sum_c (x[b,c,n]*scl[c]+sft[c]) * Wkqv[col][c] + b[col]
//   m = b*1024 + n.  128(M) x 256(N) tiles, K-step 32.
// grid 768 = 256 m-tiles x 3 col-tiles; bid decode keeps all 3 col-tiles of
// an m-tile on one XCD (bid%8 == bx%8) so the x A-panel re-reads hit L2.
// by 0/1 -> qk[m][col] (bf16); by 2 -> vt[b][col-512][n] (transposed store).
// A-tile: each thread loads 16 fp32 (coalesced 128-lane rows of x), applies
// scale/shift, f2bf (same rounding as before), packs 2x ds_write_b128 with
// XOR chunk swizzle (chunk ^= (row>>1)&3) -- write- and read-conflict-free.
__global__ __launch_bounds__(256, 2) void qkv_fused_kernel(
    const float* __restrict__ x, const float* __restrict__ scl,
    const float* __restrict__ sft, const u16* __restrict__ Wkb,
    const u16* __restrict__ bkb, u16* __restrict__ qkout, u16* __restrict__ vt)
{
  __shared__ __align__(16) u16 As[128 * 32];   // 8 KB, swizzled
  __shared__ __align__(16) u16 Bs[256 * 32];   // 16 KB, linear (gld16)
  int bid = blockIdx.x;
  int bx = bid & 255, by = bid >> 8;           // by = 0..2
  int b = bx >> 3, nsp0 = (bx & 7) * 128;
  int tid = threadIdx.x, lane = tid & 63, w = tid >> 6;
  int lq = lane & 15, quad = lane >> 4;
  int wm = (w >> 1) * 64, wn = (w & 1) * 128;
  int ar = lane >> 2, ac = (lane & 3) * 8;     // B staging: 4 lanes/row, 16B
  int rbB = w * 64;                            // wave's 64-row B slice
  int nn = tid & 127, ci0 = (tid >> 7) * 16;   // A staging: row nn, cols ci0..+16

  const float* xb = x + (((size_t)(b * CC)) << 10) + nsp0 + nn;
  const u16* Bw = Wkb + (size_t)(by * 256) * 256;

  f32x4 zero = {0.f, 0.f, 0.f, 0.f};
  f32x4 acc[4][8];
  #pragma unroll
  for (int i = 0; i < 4; ++i)
    #pragma unroll
    for (int j = 0; j < 8; ++j) acc[i][j] = zero;

  int swz = (nn >> 1) & 3;
  int jj0 = ci0 >> 3;                          // 0 or 2

  for (int k0 = 0; k0 < 256; k0 += 32) {
    __syncthreads();   // previous tile's ds_reads complete before overwrite
    // B: 256 rows x 32 cols via global_load_lds
    #pragma unroll
    for (int i = 0; i < 4; ++i)
      gld16(Bw + (size_t)(rbB + i * 16 + ar) * 256 + k0 + ac,
            &Bs[(rbB + i * 16) * 32]);
    // A: 16 fp32 loads (stride 4KB, coalesced across the 128-lane group),
    // normalize, convert, pack, 2x swizzled b128 LDS writes
    float sv[16], hv[16];
    #pragma unroll
    for (int g = 0; g < 4; ++g) {
      float4 a = *reinterpret_cast<const float4*>(scl + k0 + ci0 + g * 4);
      float4 d = *reinterpret_cast<const float4*>(sft + k0 + ci0 + g * 4);
      sv[g * 4 + 0] = a.x; sv[g * 4 + 1] = a.y; sv[g * 4 + 2] = a.z; sv[g * 4 + 3] = a.w;
      hv[g * 4 + 0] = d.x; hv[g * 4 + 1] = d.y; hv[g * 4 + 2] = d.z; hv[g * 4 + 3] = d.w;
    }
    u16 av[16];
    #pragma unroll
    for (int i = 0; i < 16; ++i) {
      float v = xb[((size_t)(k0 + ci0 + i)) << 10];
      av[i] = f2bf(v * sv[i] + hv[i]);
    }
    bf16x8 p0, p1;
    #pragma unroll
    for (int i = 0; i < 8; ++i) { p0[i] = (short)av[i]; p1[i] = (short)av[i + 8]; }
    *reinterpret_cast<bf16x8*>(&As[nn * 32 + ((jj0 ^ swz) << 3)]) = p0;
    *reinterpret_cast<bf16x8*>(&As[nn * 32 + (((jj0 + 1) ^ swz) << 3)]) = p1;
    __syncthreads();   // drains lgkm (writes) + vmcnt (gld16)

    bf16x8 af[4], bfr[8];
    #pragma unroll
    for (int i = 0; i < 4; ++i) {
      int r = wm + i * 16 + lq;
      af[i] = *reinterpret_cast<const bf16x8*>(
          &As[r * 32 + ((quad ^ ((r >> 1) & 3)) << 3)]);
    }
    #pragma unroll
    for (int j = 0; j < 8; ++j)
      bfr[j] = *reinterpret_cast<const bf16x8*>(
          &Bs[(wn + j * 16 + lq) * 32 + quad * 8]);
    #pragma unroll
    for (int i = 0; i < 4; ++i)
      #pragma unroll
      for (int j = 0; j < 8; ++j)
        acc[i][j] = __builtin_amdgcn_mfma_f32_16x16x32_bf16(af[i], bfr[j], acc[i][j], 0, 0, 0);
  }

  if (by < 2) {
    // qk store: [m][col], col = by*256 + ...
    #pragma unroll
    for (int j = 0; j < 8; ++j) {
      int col = by * 256 + wn + j * 16 + lq;
      float bv = bf2f(bkb[col]);
      #pragma unroll
      for (int i = 0; i < 4; ++i) {
        int m = (b << 10) + nsp0 + wm + i * 16 + quad * 4;
        #pragma unroll
        for (int r = 0; r < 4; ++r)
          qkout[(size_t)(m + r) * 512 + col] = f2bf(acc[i][j][r] + bv);
      }
    }
  } else {
    // vt store: vt[b][col][n], transposed ushort4 along n
    #pragma unroll
    for (int j = 0; j < 8; ++j) {
      int col = wn + j * 16 + lq;
      float bv = bf2f(bkb[512 + col]);
      #pragma unroll
      for (int i = 0; i < 4; ++i) {
        int n = nsp0 + wm + i * 16 + quad * 4;
        ushort4 o;
        o.x = f2bf(acc[i][j][0] + bv);
        o.y = f2bf(acc[i][j][1] + bv);
        o.z = f2bf(acc[i][j][2] + bv);
        o.w = f2bf(acc[i][j][3] + bv);
        *reinterpret_cast<ushort4*>(&vt[(size_t)b * 262144 + (size_t)col * 1024 + n]) = o;
      }
    }
  }
}

// ---------------- 3. NT bf16 GEMM, m97 structure (global_load_lds staging) ---
// C[m,n] = f(scale * sum_k A[m,k]*B[n,k] + bias[n])
// mode 0: plain bf16 store
// mode 2: proj + residual: outf[(b*256+col)<<10 | n] = v + xres[...] (fp32)
__global__ __launch_bounds__(256) void gemm_nt_kernel(
    const u16* __restrict__ A, int lda, size_t sA,
    const u16* __restrict__ B, int ldb, size_t sB,
    u16* __restrict__ C, int ldc, size_t sC,
    int K, const u16* __restrict__ bias, float scale, int mode,
    const float* __restrict__ xres, float* __restrict__ outf)
{
  __shared__ u16 As[128 * 32];   // unpadded: global_load_lds needs lane-contiguous
  __shared__ u16 Bs[128 * 32];
  int tid = threadIdx.x;
  int m0 = blockIdx.x * 128, n0 = blockIdx.y * 128;
  const u16* Ab = A + (size_t)blockIdx.z * sA;
  const u16* Bb = B + (size_t)blockIdx.z * sB;
  u16* Cb = C + (size_t)blockIdx.z * sC;

  int lane = tid & 63, w = tid >> 6;
  int lq = lane & 15, quad = lane >> 4;
  int wm = (w >> 1) * 64, wn = (w & 1) * 64;
  int ar = lane >> 2, ac = (lane & 3) * 8;   // staging: 4 lanes/row, 16B each
  int rb = w * 32;                            // wave's 32-row staging slice

  f32x4 zero = {0.f, 0.f, 0.f, 0.f};
  f32x4 acc[4][4];
  #pragma unroll
  for (int i = 0; i < 4; ++i)
    #pragma unroll
    for (int j = 0; j < 4; ++j) acc[i][j] = zero;

  for (int k0 = 0; k0 < K; k0 += 32) {
    __syncthreads();   // previous tile's ds_reads complete before overwrite
    gld16(Ab + (size_t)(m0 + rb +      ar) * lda + k0 + ac, &As[(rb     ) * 32]);
    gld16(Ab + (size_t)(m0 + rb + 16 + ar) * lda + k0 + ac, &As[(rb + 16) * 32]);
    gld16(Bb + (size_t)(n0 + rb +      ar) * ldb + k0 + ac, &Bs[(rb     ) * 32]);
    gld16(Bb + (size_t)(n0 + rb + 16 + ar) * ldb + k0 + ac, &Bs[(rb + 16) * 32]);
    __syncthreads();   // compiler drains vmcnt before barrier
    bf16x8 af[4], bfr[4];
    #pragma unroll
    for (int i = 0; i < 4; ++i) {
      af[i]  = *reinterpret_cast<const bf16x8*>(&As[(wm + i * 16 + lq) * 32 + quad * 8]);
      bfr[i] = *reinterpret_cast<const bf16x8*>(&Bs[(wn + i * 16 + lq) * 32 + quad * 8]);
    }
    #pragma unroll
    for (int i = 0; i < 4; ++i)
      #pragma unroll
      for (int j = 0; j < 4; ++j)
        acc[i][j] = __builtin_amdgcn_mfma_f32_16x16x32_bf16(af[i], bfr[j], acc[i][j], 0, 0, 0);
  }

  #pragma unroll
  for (int j = 0; j < 4; ++j) {
    int col = n0 + wn + j * 16 + lq;
    float bv = bias ? bf2f(bias[col]) : 0.f;
    #pragma unroll
    for (int i = 0; i < 4; ++i) {
      int rbase = m0 + wm + i * 16 + quad * 4;
      if (mode == 2) {
        int b = rbase >> 10, n = rbase & 1023;
        size_t idx = (((size_t)(b * CC + col)) << 10) + n;
        float4 xv = *reinterpret_cast<const float4*>(xres + idx);
        float4 o;
        o.x = acc[i][j][0] * scale + bv + xv.x;
        o.y = acc[i][j][1] * scale + bv + xv.y;
        o.z = acc[i][j][2] * scale + bv + xv.z;
        o.w = acc[i][j][3] * scale + bv + xv.w;
        *reinterpret_cast<float4*>(outf + idx) = o;
      } else {
        #pragma unroll
        for (int r = 0; r < 4; ++r)
          Cb[(size_t)(rbase + r) * ldc + col] = f2bf(acc[i][j][r] * scale + bv);
      }
    }
  }
}

// ---------------- 4. fused attention: O = softmax(Q K^T / 16) V -------------
// Producer/consumer wave specialization: 8 waves (2 per SIMD).
// Waves 0-3 (QK role): 32 q-rows each, Q in registers; compute S(p), exp,
//   write P(p) into shared LDS between the two phase barriers.
// Waves 4-7 (PV role): 64 output-cols each x all 128 rows; compute
//   O += P(p-1) * V(p-1) -- overlaps QK(p) on the same SIMDs.
// K/V double-buffered (staged via global_load_lds, pre-swizzled source),
// P single-buffered with a 2-barrier handoff. Per-role loops with matched
// raw-barrier counts (36 each); rowsum handoff via LDS at the end.
__global__ __launch_bounds__(512, 2) void attn_kernel(
    const u16* __restrict__ qk,   // [B*1024, 512]: Q = cols 0:256, K = 256:512
    const u16* __restrict__ vt,   // [B, 256, 1024]: V^T per batch
    u16* __restrict__ o)          // [B*1024, 256]
{
  __shared__ __align__(16) u16 Ks[2][64 * 256];   // 2x32 KB [kr][c], chunk^=(kr&7)
  __shared__ __align__(16) u16 Vs[2][256 * 64];   // 2x32 KB [n][k],  chunk^=(n&7)
  __shared__ __align__(16) u16 Ps[128 * 64];      // 16 KB   [q][k],  chunk^=(q&7)
  float* rs = (float*)Ps;          // 128 f32 inv-rowsums; alias ok: P dead then

  int bid = blockIdx.x;
  // XCD swizzle: all 8 q-tiles of one batch land on one XCD (K/V L2-resident)
  int b  = (bid & 7) + 8 * ((bid >> 3) & 3);
  int qt = bid >> 5;
  int tid = threadIdx.x, lane = tid & 63, w = tid >> 6;
  int lq = lane & 15, hh = lane >> 4;
  int wr = w & 3;                  // row-group (QK) / col-group (PV)
  bool isQK = w < 4;

  const u16* qb = qk + ((size_t)b << 10) * 512;
  const u16* kb = qb + 256;
  const u16* vb = vt + ((size_t)b << 18);

  // staging: 512 threads, 4 chunks(16B) each per tile half
  auto stageK = [&](int kt, int bufi) {
    #pragma unroll
    for (int i = 0; i < 4; ++i) {
      int slot = i * 512 + tid;
      int r = slot >> 5, c = slot & 31;
      gld16(kb + (size_t)(kt * 64 + r) * 512 + ((c ^ (r & 7)) << 3),
            &Ks[bufi][(i * 512 + (tid & 448)) * 8]);
    }
  };
  auto stageV = [&](int kt, int bufi) {
    #pragma unroll
    for (int i = 0; i < 4; ++i) {
      int slot = i * 512 + tid;
      int n = slot >> 3, c = slot & 7;
      gld16(vb + (size_t)(n << 10) + kt * 64 + ((c ^ (n & 7)) << 3),
            &Vs[bufi][(i * 512 + (tid & 448)) * 8]);
    }
  };

  f32x4 zero = {0.f, 0.f, 0.f, 0.f};

  // prologue: stage K(0) into buf0 (common, uniform)
  stageK(0, 0);
  SYNCB();                                   // barrier #1

  if (isQK) {
    // ---------------- QK / softmax producer ----------------
    int q0 = qt * 128 + wr * 32;
    bf16x8 qf[2][8];
    #pragma unroll
    for (int qi = 0; qi < 2; ++qi)
      #pragma unroll
      for (int kk = 0; kk < 8; ++kk)
        qf[qi][kk] = *reinterpret_cast<const bf16x8*>(
            qb + (size_t)(q0 + qi * 16 + lq) * 512 + kk * 32 + hh * 8);
    float runsum[2][4] = {{0.f, 0.f, 0.f, 0.f}, {0.f, 0.f, 0.f, 0.f}};

    #pragma unroll 1
    for (int p = 0; p <= 16; ++p) {
      if (p <= 15) stageV(p, p & 1);
      if (p <= 14) stageK(p + 1, (p + 1) & 1);
      u16 pbv[2][4][4];
      if (p <= 15) {
        const u16* Kc = Ks[p & 1];
        f32x4 sacc[2][4];
        #pragma unroll
        for (int qi = 0; qi < 2; ++qi)
          #pragma unroll
          for (int ni = 0; ni < 4; ++ni) sacc[qi][ni] = zero;
        #pragma unroll
        for (int kk = 0; kk < 8; ++kk) {
          bf16x8 kf[4];
          #pragma unroll
          for (int ni = 0; ni < 4; ++ni) {
            int r = ni * 16 + lq;
            kf[ni] = *reinterpret_cast<const bf16x8*>(
                &Kc[r * 256 + (((kk * 4 + hh) ^ (r & 7)) << 3)]);
          }
          __builtin_amdgcn_s_setprio(1);
          #pragma unroll
          for (int qi = 0; qi < 2; ++qi)
            #pragma unroll
            for (int ni = 0; ni < 4; ++ni)
              sacc[qi][ni] = __builtin_amdgcn_mfma_f32_16x16x32_bf16(
                  qf[qi][kk], kf[ni], sacc[qi][ni], 0, 0, 0);
          __builtin_amdgcn_s_setprio(0);
        }
        // softmax numerator into regs (write deferred past barrier A)
        #pragma unroll
        for (int qi = 0; qi < 2; ++qi)
          #pragma unroll
          for (int ni = 0; ni < 4; ++ni)
            #pragma unroll
            for (int rr = 0; rr < 4; ++rr) {
              float pexp = __expf(sacc[qi][ni][rr] * 0.0625f);
              u16 pb = f2bf(pexp);
              runsum[qi][rr] += bf2f(pb);   // sum rounded values (= PV input)
              pbv[qi][ni][rr] = pb;
            }
      }
      SYNCB();                               // phase barrier A
      if (p <= 15) {
        #pragma unroll
        for (int qi = 0; qi < 2; ++qi)
          #pragma unroll
          for (int ni = 0; ni < 4; ++ni)
            #pragma unroll
            for (int rr = 0; rr < 4; ++rr) {
              int q = wr * 32 + qi * 16 + hh * 4 + rr;
              int kcol = ni * 16 + lq;
              Ps[q * 64 + ((((kcol >> 3) ^ (q & 7)) << 3) | (kcol & 7))] =
                  pbv[qi][ni][rr];
            }
      }
      SYNCB();                               // phase barrier B
    }

    // inv-rowsums -> LDS for the PV waves
    #pragma unroll
    for (int qi = 0; qi < 2; ++qi)
      #pragma unroll
      for (int rr = 0; rr < 4; ++rr) {
        float s = runsum[qi][rr];
        s += __shfl_xor(s, 1, 64);
        s += __shfl_xor(s, 2, 64);
        s += __shfl_xor(s, 4, 64);
        s += __shfl_xor(s, 8, 64);
        if (lq == 0) rs[wr * 32 + qi * 16 + hh * 4 + rr] = 1.f / s;
      }
    SYNCB();                                 // final barrier
  } else {
    // ---------------- PV consumer ----------------
    f32x4 oacc[8][4];
    #pragma unroll
    for (int qi = 0; qi < 8; ++qi)
      #pragma unroll
      for (int nj = 0; nj < 4; ++nj) oacc[qi][nj] = zero;

    #pragma unroll 1
    for (int p = 0; p <= 16; ++p) {
      if (p <= 15) stageV(p, p & 1);
      if (p <= 14) stageK(p + 1, (p + 1) & 1);
      if (p >= 1) {
        const u16* Vc = Vs[(p - 1) & 1];
        #pragma unroll
        for (int kk2 = 0; kk2 < 2; ++kk2) {
          bf16x8 pa[8];
          #pragma unroll
          for (int qi = 0; qi < 8; ++qi) {
            int r = qi * 16 + lq;
            pa[qi] = *reinterpret_cast<const bf16x8*>(
                &Ps[r * 64 + (((kk2 * 4 + hh) ^ (r & 7)) << 3)]);
          }
          bf16x8 vf[4];
          #pragma unroll
          for (int nj = 0; nj < 4; ++nj) {
            int n = wr * 64 + nj * 16 + lq;
            vf[nj] = *reinterpret_cast<const bf16x8*>(
                &Vc[n * 64 + (((kk2 * 4 + hh) ^ (n & 7)) << 3)]);
          }
          __builtin_amdgcn_s_setprio(1);
          #pragma unroll
          for (int qi = 0; qi < 8; ++qi)
            #pragma unroll
            for (int nj = 0; nj < 4; ++nj)
              oacc[qi][nj] = __builtin_amdgcn_mfma_f32_16x16x32_bf16(
                  pa[qi], vf[nj], oacc[qi][nj], 0, 0, 0);
          __builtin_amdgcn_s_setprio(0);
        }
      }
      SYNCB();                               // phase barrier A
      SYNCB();                               // phase barrier B
    }

    SYNCB();                                 // final barrier (rowsums ready)
    float rinv[8][4];
    #pragma unroll
    for (int qi = 0; qi < 8; ++qi)
      #pragma unroll
      for (int rr = 0; rr < 4; ++rr)
        rinv[qi][rr] = rs[qi * 16 + hh * 4 + rr];
    u16* ob = o + ((size_t)(b << 10) + qt * 128) * 256;
    #pragma unroll
    for (int qi = 0; qi < 8; ++qi)
      #pragma unroll
      for (int nj = 0; nj < 4; ++nj)
        #pragma unroll
        for (int rr = 0; rr < 4; ++rr)
          ob[(size_t)(qi * 16 + hh * 4 + rr) * 256 + wr * 64 + nj * 16 + lq] =
              f2bf(oacc[qi][nj][rr] * rinv[qi][rr]);
  }
}

extern "C" void kernel_launch(void* const* d_in, const int* in_sizes, int n_in,
                              void* d_out, int out_size, void* d_ws, size_t ws_size,
                              hipStream_t stream) {
  const float* x     = (const float*)d_in[0];
  const float* gamma = (const float*)d_in[1];
  const float* beta  = (const float*)d_in[2];
  const float* Wkqv  = (const float*)d_in[3];
  const float* bkqv  = (const float*)d_in[4];
  const float* Wproj = (const float*)d_in[5];
  const float* bproj = (const float*)d_in[6];
  float* out = (float*)d_out;          // fp32 [32,256,32,32]

  // ---- workspace layout ----
  char* ws = (char*)d_ws;
  float* scl    = (float*)ws;                   // 256 f32
  float* sft    = (float*)(ws + 1024);          // 256 f32
  u16* Wkb = (u16*)(ws + 4096);                 // 196608 bf16
  u16* bkb = Wkb + 196608;
  u16* Wpb = bkb + 768;
  u16* bpb = Wpb + 65536;
  u16* qk   = (u16*)(ws + 1048576);             // [32768,512] bf16 = 32 MB
  u16* vt   = qk + (size_t)32768 * 512;         // [32,256,1024] bf16 = 16 MB
  u16* o_pv = vt + (size_t)32 * 256 * 1024;     // [32768,256] bf16 = 16 MB

  // 0. weight conversion
  convert_w_kernel<<<dim3(1028), dim3(256), 0, stream>>>(
      Wkqv, bkqv, Wproj, bproj, Wkb, bkb, Wpb, bpb);
  // 1. BN stats
  bn_stats_kernel<<<dim3(256), dim3(256), 0, stream>>>(x, gamma, beta, scl, sft);
  // 2. fused BN-normalize + QKV GEMM: qk (Q,K) + vt (V transposed)
  qkv_fused_kernel<<<dim3(768), dim3(256), 0, stream>>>(
      x, scl, sft, Wkb, bkb, qk, vt);
  // 3. fused attention (wave-specialized): o_pv = softmax(Q K^T / 16) V (bf16)
  attn_kernel<<<dim3(256), dim3(512), 0, stream>>>(qk, vt, o_pv);
  // 4. fused proj + residual: out[b,c,n] = (o_pv @ Wproj^T + bproj)[n,c] + x[b,c,n]
  gemm_nt_kernel<<<dim3(256, 2, 1), dim3(256), 0, stream>>>(
      o_pv, 256, 0, Wpb, 256, 0, nullptr, 0, 0, 256, bpb, 1.0f, 2, x, out);
}

// Round 6
// 197.430 us; speedup vs baseline: 1.1506x; 1.0323x over previous
//
#include <hip/hip_runtime.h>

typedef unsigned short u16;
typedef __attribute__((ext_vector_type(8))) short bf16x8;
typedef __attribute__((ext_vector_type(4))) float f32x4;

__device__ __forceinline__ float bf2f(u16 u) {
  union { unsigned u; float f; } c; c.u = ((unsigned)u) << 16; return c.f;
}
__device__ __forceinline__ u16 f2bf(float f) {
  union { float f; unsigned u; } c; c.f = f;
  unsigned u = c.u;
  return (u16)((u + 0x7FFFu + ((u >> 16) & 1u)) >> 16);
}
// async global->LDS, 16B per lane; LDS dest = wave-uniform base + lane*16
__device__ __forceinline__ void gld16(const void* g, void* l) {
  __builtin_amdgcn_global_load_lds(
      (__attribute__((address_space(1))) void*)g,
      (__attribute__((address_space(3))) void*)l, 16, 0, 0);
}

// drain own counters, then workgroup barrier (used in wave-role-divergent
// code where __syncthreads' convergence assumption doesn't hold; barrier
// counts are matched exactly across roles). sched_barrier stops hipcc from
// hoisting ds_reads/MFMA across the asm waitcnt (guide rule #18).
#define SYNCB() do { \
  asm volatile("s_waitcnt vmcnt(0) lgkmcnt(0)" ::: "memory"); \
  __builtin_amdgcn_s_barrier(); \
  __builtin_amdgcn_sched_barrier(0); \
} while (0)

#define BB 32      // batch
#define CC 256     // channels
#define NN 1024    // H*W

// ---------------- 0. convert weights/biases fp32 -> bf16 --------------------
__global__ __launch_bounds__(256) void convert_w_kernel(
    const float* __restrict__ Wk, const float* __restrict__ bk,
    const float* __restrict__ Wp, const float* __restrict__ bp,
    u16* __restrict__ Wkb, u16* __restrict__ bkb,
    u16* __restrict__ Wpb, u16* __restrict__ bpb)
{
  int b = blockIdx.x, t = threadIdx.x;
  const float* src; u16* dst; int idx, n;
  if (b < 768)       { src = Wk; dst = Wkb; idx = b * 256 + t;        n = 196608; }
  else if (b < 771)  { src = bk; dst = bkb; idx = (b - 768) * 256 + t; n = 768;   }
  else if (b < 1027) { src = Wp; dst = Wpb; idx = (b - 771) * 256 + t; n = 65536; }
  else               { src = bp; dst = bpb; idx = t;                  n = 256;    }
  if (idx < n) dst[idx] = f2bf(src[idx]);
}

// ---------------- 1. BatchNorm stats: per-channel mean/var -> scale/shift ----
__global__ __launch_bounds__(256) void bn_stats_kernel(
    const float* __restrict__ x, const float* __restrict__ gamma,
    const float* __restrict__ beta, float* __restrict__ scl, float* __restrict__ sft)
{
  int c = blockIdx.x;
  int tid = threadIdx.x;
  float s = 0.f, q = 0.f;
  for (int g = tid; g < 8192; g += 256) {
    int b = g >> 8;
    int n = (g & 255) * 4;
    float4 v = *reinterpret_cast<const float4*>(x + (((size_t)(b * CC + c)) << 10) + n);
    s += v.x + v.y + v.z + v.w;
    q += v.x * v.x + v.y * v.y + v.z * v.z + v.w * v.w;
  }
  __shared__ float rs[256], rq[256];
  rs[tid] = s; rq[tid] = q;
  __syncthreads();
  for (int off = 128; off > 0; off >>= 1) {
    if (tid < off) { rs[tid] += rs[tid + off]; rq[tid] += rq[tid + off]; }
    __syncthreads();
  }
  if (tid == 0) {
    float mean = rs[0] * (1.f / 32768.f);
    float var  = rq[0] * (1.f / 32768.f) - mean * mean;
    float rstd = rsqrtf(var + 1e-5f);
    float g = gamma[c] * rstd;
    scl[c] = g;
    sft[c] = beta[c] - mean * g;
  }
}

// ---------------- 2. fused QKV GEMM with on-the-fly BN-normalize+transpose --
// C[m, col] = sum_c (x[b,c,n]*scl[c]+sft[c]) * Wkqv[col][c] + b[col]
//   m = b*1024 + n.  128(M) x 256(N) tiles, K-step 32, SW-pipelined with
// counted vmcnt and TWO barriers per step (race-fix over round-5):
//   top:    issue B(t+1) gld16 x4 + x(t+1) reg-loads x16   (20 VMEM ops)
//   wait:   s_waitcnt vmcnt(20)  -- retires exactly B(t)+x(t); t+1 stays
//           in flight (never drained to 0 in the loop)
//   stage:  normalize x(t) -> swizzled ds_write As[t&1]
//   B1:     lgkmcnt(0) + s_barrier   (tile-t staging visible)
//   mfma:   ds_read frags + 32 MFMA from As/Bs[t&1]
//   B2:     lgkmcnt(0) + s_barrier   (all readers of tile-t buffers done;
//           ONLY this makes the next step's gld16 overwrite of Bs[(t+2)&1]
//           safe -- round-5's single-barrier version raced exactly here)
// scl/sft cached in LDS (SS) so per-step VMEM count is exactly 20.
// grid 768 = 256 m-tiles x 3 col-tiles; bid decode keeps all 3 col-tiles of
// an m-tile on one XCD (bid%8 == bx%8) so the x A-panel re-reads hit L2.
// by 0/1 -> qk[m][col] (bf16); by 2 -> vt[b][col-512][n] (transposed store).
__global__ __launch_bounds__(256, 2) void qkv_fused_kernel(
    const float* __restrict__ x, const float* __restrict__ scl,
    const float* __restrict__ sft, const u16* __restrict__ Wkb,
    const u16* __restrict__ bkb, u16* __restrict__ qkout, u16* __restrict__ vt)
{
  __shared__ __align__(16) u16 As[2][128 * 32];   // 2x8 KB, swizzled
  __shared__ __align__(16) u16 Bs[2][256 * 32];   // 2x16 KB, linear (gld16)
  __shared__ __align__(16) float SS[512];         // scl[0:256], sft[256:512]
  int bid = blockIdx.x;
  int bx = bid & 255, by = bid >> 8;           // by = 0..2
  int b = bx >> 3, nsp0 = (bx & 7) * 128;
  int tid = threadIdx.x, lane = tid & 63, w = tid >> 6;
  int lq = lane & 15, quad = lane >> 4;
  int wm = (w >> 1) * 64, wn = (w & 1) * 128;
  int ar = lane >> 2, ac = (lane & 3) * 8;     // B staging: 4 lanes/row, 16B
  int rbB = w * 64;                            // wave's 64-row B slice
  int nn = tid & 127, ci0 = (tid >> 7) * 16;   // A staging: row nn, cols ci0..+16

  const float* xb = x + (((size_t)(b * CC)) << 10) + nsp0 + nn;
  const u16* Bw = Wkb + (size_t)(by * 256) * 256;

  f32x4 zero = {0.f, 0.f, 0.f, 0.f};
  f32x4 acc[4][8];
  #pragma unroll
  for (int i = 0; i < 4; ++i)
    #pragma unroll
    for (int j = 0; j < 8; ++j) acc[i][j] = zero;

  int swz = (nn >> 1) & 3;
  int jj0 = ci0 >> 3;                          // 0 or 2

  // ---- prologue: scl/sft -> LDS, then barrier, then first prefetches ----
  if (tid < 128) {
    const float* src = (tid < 64) ? (scl + tid * 4) : (sft + (tid - 64) * 4);
    float4 v = *reinterpret_cast<const float4*>(src);
    *reinterpret_cast<float4*>(&SS[(tid < 64) ? tid * 4 : 256 + (tid - 64) * 4]) = v;
  }
  __syncthreads();   // SS visible; drains the trivial prologue vmem

  float xA[16], xB[16];
  #pragma unroll
  for (int i = 0; i < 4; ++i)
    gld16(Bw + (size_t)(rbB + i * 16 + ar) * 256 + ac, &Bs[0][(rbB + i * 16) * 32]);
  #pragma unroll
  for (int i = 0; i < 16; ++i)
    xA[i] = xb[((size_t)(ci0 + i)) << 10];

  // one pipeline step: consumes x(t) from xc + Bs/As[t&1]; prefetches t+1 into xn
  auto body = [&](int t, float (&xc)[16], float (&xn)[16]) {
    int k0 = t * 32;
    if (t < 7) {
      int kn = k0 + 32;
      // safe to overwrite Bs[(t+1)&1]: its last readers (step t-1) drained
      // their ds_reads before B2(t-1), and we are past B2(t-1) here.
      #pragma unroll
      for (int i = 0; i < 4; ++i)
        gld16(Bw + (size_t)(rbB + i * 16 + ar) * 256 + kn + ac,
              &Bs[(t + 1) & 1][(rbB + i * 16) * 32]);
      #pragma unroll
      for (int i = 0; i < 16; ++i)
        xn[i] = xb[((size_t)(kn + ci0 + i)) << 10];
    }
    // scale/shift from LDS (broadcast reads, lgkm -- doesn't disturb vmcnt)
    float sv[16], hv[16];
    #pragma unroll
    for (int g = 0; g < 4; ++g) {
      f32x4 a = *reinterpret_cast<const f32x4*>(&SS[k0 + ci0 + g * 4]);
      f32x4 d = *reinterpret_cast<const f32x4*>(&SS[256 + k0 + ci0 + g * 4]);
      sv[g * 4 + 0] = a[0]; sv[g * 4 + 1] = a[1]; sv[g * 4 + 2] = a[2]; sv[g * 4 + 3] = a[3];
      hv[g * 4 + 0] = d[0]; hv[g * 4 + 1] = d[1]; hv[g * 4 + 2] = d[2]; hv[g * 4 + 3] = d[3];
    }
    if (t < 7) {
      asm volatile("s_waitcnt vmcnt(20)" ::: "memory");  // B(t)+x(t) done; t+1 in flight
    } else {
      asm volatile("s_waitcnt vmcnt(0)" ::: "memory");
    }
    __builtin_amdgcn_sched_barrier(0);
    // normalize, convert (same rounding path as reference chain), pack, write
    u16 av[16];
    #pragma unroll
    for (int i = 0; i < 16; ++i)
      av[i] = f2bf(xc[i] * sv[i] + hv[i]);
    bf16x8 p0, p1;
    #pragma unroll
    for (int i = 0; i < 8; ++i) { p0[i] = (short)av[i]; p1[i] = (short)av[i + 8]; }
    *reinterpret_cast<bf16x8*>(&As[t & 1][nn * 32 + ((jj0 ^ swz) << 3)]) = p0;
    *reinterpret_cast<bf16x8*>(&As[t & 1][nn * 32 + (((jj0 + 1) ^ swz) << 3)]) = p1;
    asm volatile("s_waitcnt lgkmcnt(0)" ::: "memory");   // ds_writes visible
    __builtin_amdgcn_s_barrier();                        // B1: tile-t staged
    __builtin_amdgcn_sched_barrier(0);

    bf16x8 af[4], bfr[8];
    #pragma unroll
    for (int i = 0; i < 4; ++i) {
      int r = wm + i * 16 + lq;
      af[i] = *reinterpret_cast<const bf16x8*>(
          &As[t & 1][r * 32 + ((quad ^ ((r >> 1) & 3)) << 3)]);
    }
    #pragma unroll
    for (int j = 0; j < 8; ++j)
      bfr[j] = *reinterpret_cast<const bf16x8*>(
          &Bs[t & 1][(wn + j * 16 + lq) * 32 + quad * 8]);
    __builtin_amdgcn_s_setprio(1);
    #pragma unroll
    for (int i = 0; i < 4; ++i)
      #pragma unroll
      for (int j = 0; j < 8; ++j)
        acc[i][j] = __builtin_amdgcn_mfma_f32_16x16x32_bf16(af[i], bfr[j], acc[i][j], 0, 0, 0);
    __builtin_amdgcn_s_setprio(0);
    asm volatile("s_waitcnt lgkmcnt(0)" ::: "memory");   // own frag reads done
    __builtin_amdgcn_s_barrier();                        // B2: buffers reusable
    __builtin_amdgcn_sched_barrier(0);
  };

  #pragma unroll 1
  for (int tt = 0; tt < 4; ++tt) {
    body(2 * tt,     xA, xB);
    body(2 * tt + 1, xB, xA);
  }

  if (by < 2) {
    // qk store: [m][col], col = by*256 + ...
    #pragma unroll
    for (int j = 0; j < 8; ++j) {
      int col = by * 256 + wn + j * 16 + lq;
      float bv = bf2f(bkb[col]);
      #pragma unroll
      for (int i = 0; i < 4; ++i) {
        int m = (b << 10) + nsp0 + wm + i * 16 + quad * 4;
        #pragma unroll
        for (int r = 0; r < 4; ++r)
          qkout[(size_t)(m + r) * 512 + col] = f2bf(acc[i][j][r] + bv);
      }
    }
  } else {
    // vt store: vt[b][col][n], transposed ushort4 along n
    #pragma unroll
    for (int j = 0; j < 8; ++j) {
      int col = wn + j * 16 + lq;
      float bv = bf2f(bkb[512 + col]);
      #pragma unroll
      for (int i = 0; i < 4; ++i) {
        int n = nsp0 + wm + i * 16 + quad * 4;
        ushort4 o;
        o.x = f2bf(acc[i][j][0] + bv);
        o.y = f2bf(acc[i][j][1] + bv);
        o.z = f2bf(acc[i][j][2] + bv);
        o.w = f2bf(acc[i][j][3] + bv);
        *reinterpret_cast<ushort4*>(&vt[(size_t)b * 262144 + (size_t)col * 1024 + n]) = o;
      }
    }
  }
}

// ---------------- 3. NT bf16 GEMM, m97 structure (global_load_lds staging) ---
// C[m,n] = f(scale * sum_k A[m,k]*B[n,k] + bias[n])
// mode 0: plain bf16 store
// mode 2: proj + residual: outf[(b*256+col)<<10 | n] = v + xres[...] (fp32)
__global__ __launch_bounds__(256) void gemm_nt_kernel(
    const u16* __restrict__ A, int lda, size_t sA,
    const u16* __restrict__ B, int ldb, size_t sB,
    u16* __restrict__ C, int ldc, size_t sC,
    int K, const u16* __restrict__ bias, float scale, int mode,
    const float* __restrict__ xres, float* __restrict__ outf)
{
  __shared__ u16 As[128 * 32];   // unpadded: global_load_lds needs lane-contiguous
  __shared__ u16 Bs[128 * 32];
  int tid = threadIdx.x;
  int m0 = blockIdx.x * 128, n0 = blockIdx.y * 128;
  const u16* Ab = A + (size_t)blockIdx.z * sA;
  const u16* Bb = B + (size_t)blockIdx.z * sB;
  u16* Cb = C + (size_t)blockIdx.z * sC;

  int lane = tid & 63, w = tid >> 6;
  int lq = lane & 15, quad = lane >> 4;
  int wm = (w >> 1) * 64, wn = (w & 1) * 64;
  int ar = lane >> 2, ac = (lane & 3) * 8;   // staging: 4 lanes/row, 16B each
  int rb = w * 32;                            // wave's 32-row staging slice

  f32x4 zero = {0.f, 0.f, 0.f, 0.f};
  f32x4 acc[4][4];
  #pragma unroll
  for (int i = 0; i < 4; ++i)
    #pragma unroll
    for (int j = 0; j < 4; ++j) acc[i][j] = zero;

  for (int k0 = 0; k0 < K; k0 += 32) {
    __syncthreads();   // previous tile's ds_reads complete before overwrite
    gld16(Ab + (size_t)(m0 + rb +      ar) * lda + k0 + ac, &As[(rb     ) * 32]);
    gld16(Ab + (size_t)(m0 + rb + 16 + ar) * lda + k0 + ac, &As[(rb + 16) * 32]);
    gld16(Bb + (size_t)(n0 + rb +      ar) * ldb + k0 + ac, &Bs[(rb     ) * 32]);
    gld16(Bb + (size_t)(n0 + rb + 16 + ar) * ldb + k0 + ac, &Bs[(rb + 16) * 32]);
    __syncthreads();   // compiler drains vmcnt before barrier
    bf16x8 af[4], bfr[4];
    #pragma unroll
    for (int i = 0; i < 4; ++i) {
      af[i]  = *reinterpret_cast<const bf16x8*>(&As[(wm + i * 16 + lq) * 32 + quad * 8]);
      bfr[i] = *reinterpret_cast<const bf16x8*>(&Bs[(wn + i * 16 + lq) * 32 + quad * 8]);
    }
    #pragma unroll
    for (int i = 0; i < 4; ++i)
      #pragma unroll
      for (int j = 0; j < 4; ++j)
        acc[i][j] = __builtin_amdgcn_mfma_f32_16x16x32_bf16(af[i], bfr[j], acc[i][j], 0, 0, 0);
  }

  #pragma unroll
  for (int j = 0; j < 4; ++j) {
    int col = n0 + wn + j * 16 + lq;
    float bv = bias ? bf2f(bias[col]) : 0.f;
    #pragma unroll
    for (int i = 0; i < 4; ++i) {
      int rbase = m0 + wm + i * 16 + quad * 4;
      if (mode == 2) {
        int b = rbase >> 10, n = rbase & 1023;
        size_t idx = (((size_t)(b * CC + col)) << 10) + n;
        float4 xv = *reinterpret_cast<const float4*>(xres + idx);
        float4 o;
        o.x = acc[i][j][0] * scale + bv + xv.x;
        o.y = acc[i][j][1] * scale + bv + xv.y;
        o.z = acc[i][j][2] * scale + bv + xv.z;
        o.w = acc[i][j][3] * scale + bv + xv.w;
        *reinterpret_cast<float4*>(outf + idx) = o;
      } else {
        #pragma unroll
        for (int r = 0; r < 4; ++r)
          Cb[(size_t)(rbase + r) * ldc + col] = f2bf(acc[i][j][r] * scale + bv);
      }
    }
  }
}

// ---------------- 4. fused attention: O = softmax(Q K^T / 16) V -------------
// Producer/consumer wave specialization: 8 waves (2 per SIMD).
// Waves 0-3 (QK role): 32 q-rows each, Q in registers; compute S(p), exp,
//   write P(p) into shared LDS between the two phase barriers.
// Waves 4-7 (PV role): 64 output-cols each x all 128 rows; compute
//   O += P(p-1) * V(p-1) -- overlaps QK(p) on the same SIMDs.
// K/V double-buffered (staged via global_load_lds, pre-swizzled source),
// P single-buffered with a 2-barrier handoff. Per-role loops with matched
// raw-barrier counts (36 each); rowsum handoff via LDS at the end.
__global__ __launch_bounds__(512, 2) void attn_kernel(
    const u16* __restrict__ qk,   // [B*1024, 512]: Q = cols 0:256, K = 256:512
    const u16* __restrict__ vt,   // [B, 256, 1024]: V^T per batch
    u16* __restrict__ o)          // [B*1024, 256]
{
  __shared__ __align__(16) u16 Ks[2][64 * 256];   // 2x32 KB [kr][c], chunk^=(kr&7)
  __shared__ __align__(16) u16 Vs[2][256 * 64];   // 2x32 KB [n][k],  chunk^=(n&7)
  __shared__ __align__(16) u16 Ps[128 * 64];      // 16 KB   [q][k],  chunk^=(q&7)
  float* rs = (float*)Ps;          // 128 f32 inv-rowsums; alias ok: P dead then

  int bid = blockIdx.x;
  // XCD swizzle: all 8 q-tiles of one batch land on one XCD (K/V L2-resident)
  int b  = (bid & 7) + 8 * ((bid >> 3) & 3);
  int qt = bid >> 5;
  int tid = threadIdx.x, lane = tid & 63, w = tid >> 6;
  int lq = lane & 15, hh = lane >> 4;
  int wr = w & 3;                  // row-group (QK) / col-group (PV)
  bool isQK = w < 4;

  const u16* qb = qk + ((size_t)b << 10) * 512;
  const u16* kb = qb + 256;
  const u16* vb = vt + ((size_t)b << 18);

  // staging: 512 threads, 4 chunks(16B) each per tile half
  auto stageK = [&](int kt, int bufi) {
    #pragma unroll
    for (int i = 0; i < 4; ++i) {
      int slot = i * 512 + tid;
      int r = slot >> 5, c = slot & 31;
      gld16(kb + (size_t)(kt * 64 + r) * 512 + ((c ^ (r & 7)) << 3),
            &Ks[bufi][(i * 512 + (tid & 448)) * 8]);
    }
  };
  auto stageV = [&](int kt, int bufi) {
    #pragma unroll
    for (int i = 0; i < 4; ++i) {
      int slot = i * 512 + tid;
      int n = slot >> 3, c = slot & 7;
      gld16(vb + (size_t)(n << 10) + kt * 64 + ((c ^ (n & 7)) << 3),
            &Vs[bufi][(i * 512 + (tid & 448)) * 8]);
    }
  };

  f32x4 zero = {0.f, 0.f, 0.f, 0.f};

  // prologue: stage K(0) into buf0 (common, uniform)
  stageK(0, 0);
  SYNCB();                                   // barrier #1

  if (isQK) {
    // ---------------- QK / softmax producer ----------------
    int q0 = qt * 128 + wr * 32;
    bf16x8 qf[2][8];
    #pragma unroll
    for (int qi = 0; qi < 2; ++qi)
      #pragma unroll
      for (int kk = 0; kk < 8; ++kk)
        qf[qi][kk] = *reinterpret_cast<const bf16x8*>(
            qb + (size_t)(q0 + qi * 16 + lq) * 512 + kk * 32 + hh * 8);
    float runsum[2][4] = {{0.f, 0.f, 0.f, 0.f}, {0.f, 0.f, 0.f, 0.f}};

    #pragma unroll 1
    for (int p = 0; p <= 16; ++p) {
      if (p <= 15) stageV(p, p & 1);
      if (p <= 14) stageK(p + 1, (p + 1) & 1);
      u16 pbv[2][4][4];
      if (p <= 15) {
        const u16* Kc = Ks[p & 1];
        f32x4 sacc[2][4];
        #pragma unroll
        for (int qi = 0; qi < 2; ++qi)
          #pragma unroll
          for (int ni = 0; ni < 4; ++ni) sacc[qi][ni] = zero;
        #pragma unroll
        for (int kk = 0; kk < 8; ++kk) {
          bf16x8 kf[4];
          #pragma unroll
          for (int ni = 0; ni < 4; ++ni) {
            int r = ni * 16 + lq;
            kf[ni] = *reinterpret_cast<const bf16x8*>(
                &Kc[r * 256 + (((kk * 4 + hh) ^ (r & 7)) << 3)]);
          }
          __builtin_amdgcn_s_setprio(1);
          #pragma unroll
          for (int qi = 0; qi < 2; ++qi)
            #pragma unroll
            for (int ni = 0; ni < 4; ++ni)
              sacc[qi][ni] = __builtin_amdgcn_mfma_f32_16x16x32_bf16(
                  qf[qi][kk], kf[ni], sacc[qi][ni], 0, 0, 0);
          __builtin_amdgcn_s_setprio(0);
        }
        // softmax numerator into regs (write deferred past barrier A)
        #pragma unroll
        for (int qi = 0; qi < 2; ++qi)
          #pragma unroll
          for (int ni = 0; ni < 4; ++ni)
            #pragma unroll
            for (int rr = 0; rr < 4; ++rr) {
              float pexp = __expf(sacc[qi][ni][rr] * 0.0625f);
              u16 pb = f2bf(pexp);
              runsum[qi][rr] += bf2f(pb);   // sum rounded values (= PV input)
              pbv[qi][ni][rr] = pb;
            }
      }
      SYNCB();                               // phase barrier A
      if (p <= 15) {
        #pragma unroll
        for (int qi = 0; qi < 2; ++qi)
          #pragma unroll
          for (int ni = 0; ni < 4; ++ni)
            #pragma unroll
            for (int rr = 0; rr < 4; ++rr) {
              int q = wr * 32 + qi * 16 + hh * 4 + rr;
              int kcol = ni * 16 + lq;
              Ps[q * 64 + ((((kcol >> 3) ^ (q & 7)) << 3) | (kcol & 7))] =
                  pbv[qi][ni][rr];
            }
      }
      SYNCB();                               // phase barrier B
    }

    // inv-rowsums -> LDS for the PV waves
    #pragma unroll
    for (int qi = 0; qi < 2; ++qi)
      #pragma unroll
      for (int rr = 0; rr < 4; ++rr) {
        float s = runsum[qi][rr];
        s += __shfl_xor(s, 1, 64);
        s += __shfl_xor(s, 2, 64);
        s += __shfl_xor(s, 4, 64);
        s += __shfl_xor(s, 8, 64);
        if (lq == 0) rs[wr * 32 + qi * 16 + hh * 4 + rr] = 1.f / s;
      }
    SYNCB();                                 // final barrier
  } else {
    // ---------------- PV consumer ----------------
    f32x4 oacc[8][4];
    #pragma unroll
    for (int qi = 0; qi < 8; ++qi)
      #pragma unroll
      for (int nj = 0; nj < 4; ++nj) oacc[qi][nj] = zero;

    #pragma unroll 1
    for (int p = 0; p <= 16; ++p) {
      if (p <= 15) stageV(p, p & 1);
      if (p <= 14) stageK(p + 1, (p + 1) & 1);
      if (p >= 1) {
        const u16* Vc = Vs[(p - 1) & 1];
        #pragma unroll
        for (int kk2 = 0; kk2 < 2; ++kk2) {
          bf16x8 pa[8];
          #pragma unroll
          for (int qi = 0; qi < 8; ++qi) {
            int r = qi * 16 + lq;
            pa[qi] = *reinterpret_cast<const bf16x8*>(
                &Ps[r * 64 + (((kk2 * 4 + hh) ^ (r & 7)) << 3)]);
          }
          bf16x8 vf[4];
          #pragma unroll
          for (int nj = 0; nj < 4; ++nj) {
            int n = wr * 64 + nj * 16 + lq;
            vf[nj] = *reinterpret_cast<const bf16x8*>(
                &Vc[n * 64 + (((kk2 * 4 + hh) ^ (n & 7)) << 3)]);
          }
          __builtin_amdgcn_s_setprio(1);
          #pragma unroll
          for (int qi = 0; qi < 8; ++qi)
            #pragma unroll
            for (int nj = 0; nj < 4; ++nj)
              oacc[qi][nj] = __builtin_amdgcn_mfma_f32_16x16x32_bf16(
                  pa[qi], vf[nj], oacc[qi][nj], 0, 0, 0);
          __builtin_amdgcn_s_setprio(0);
        }
      }
      SYNCB();                               // phase barrier A
      SYNCB();                               // phase barrier B
    }

    SYNCB();                                 // final barrier (rowsums ready)
    float rinv[8][4];
    #pragma unroll
    for (int qi = 0; qi < 8; ++qi)
      #pragma unroll
      for (int rr = 0; rr < 4; ++rr)
        rinv[qi][rr] = rs[qi * 16 + hh * 4 + rr];
    u16* ob = o + ((size_t)(b << 10) + qt * 128) * 256;
    #pragma unroll
    for (int qi = 0; qi < 8; ++qi)
      #pragma unroll
      for (int nj = 0; nj < 4; ++nj)
        #pragma unroll
        for (int rr = 0; rr < 4; ++rr)
          ob[(size_t)(qi * 16 + hh * 4 + rr) * 256 + wr * 64 + nj * 16 + lq] =
              f2bf(oacc[qi][nj][rr] * rinv[qi][rr]);
  }
}

extern "C" void kernel_launch(void* const* d_in, const int* in_sizes, int n_in,
                              void* d_out, int out_size, void* d_ws, size_t ws_size,
                              hipStream_t stream) {
  const float* x     = (const float*)d_in[0];
  const float* gamma = (const float*)d_in[1];
  const float* beta  = (const float*)d_in[2];
  const float* Wkqv  = (const float*)d_in[3];
  const float* bkqv  = (const float*)d_in[4];
  const float* Wproj = (const float*)d_in[5];
  const float* bproj = (const float*)d_in[6];
  float* out = (float*)d_out;          // fp32 [32,256,32,32]

  // ---- workspace layout ----
  char* ws = (char*)d_ws;
  float* scl    = (float*)ws;                   // 256 f32
  float* sft    = (float*)(ws + 1024);          // 256 f32
  u16* Wkb = (u16*)(ws + 4096);                 // 196608 bf16
  u16* bkb = Wkb + 196608;
  u16* Wpb = bkb + 768;
  u16* bpb = Wpb + 65536;
  u16* qk   = (u16*)(ws + 1048576);             // [32768,512] bf16 = 32 MB
  u16* vt   = qk + (size_t)32768 * 512;         // [32,256,1024] bf16 = 16 MB
  u16* o_pv = vt + (size_t)32 * 256 * 1024;     // [32768,256] bf16 = 16 MB

  // 0. weight conversion
  convert_w_kernel<<<dim3(1028), dim3(256), 0, stream>>>(
      Wkqv, bkqv, Wproj, bproj, Wkb, bkb, Wpb, bpb);
  // 1. BN stats
  bn_stats_kernel<<<dim3(256), dim3(256), 0, stream>>>(x, gamma, beta, scl, sft);
  // 2. fused BN-normalize + QKV GEMM (SW-pipelined, 2-barrier): qk + vt
  qkv_fused_kernel<<<dim3(768), dim3(256), 0, stream>>>(
      x, scl, sft, Wkb, bkb, qk, vt);
  // 3. fused attention (wave-specialized): o_pv = softmax(Q K^T / 16) V (bf16)
  attn_kernel<<<dim3(256), dim3(512), 0, stream>>>(qk, vt, o_pv);
  // 4. fused proj + residual: out[b,c,n] = (o_pv @ Wproj^T + bproj)[n,c] + x[b,c,n]
  gemm_nt_kernel<<<dim3(256, 2, 1), dim3(256), 0, stream>>>(
      o_pv, 256, 0, Wpb, 256, 0, nullptr, 0, 0, 256, bpb, 1.0f, 2, x, out);
}